// Round 13
// baseline (460.850 us; speedup 1.0000x reference)
//
#include <hip/hip_runtime.h>
#include <hip/hip_bf16.h>

// GAT-style graph attention. N=50000, E=600000, FEAT=128, H=8, D=16.
// R13: binned CSR fill, fixed. R12 crashed: atomic-order scan blocks gave
//      non-contiguous offset ranges per bucket -> overlapping staging ->
//      garbage records -> OOB. Now scan block == bucket (512 dests), so
//      each bucket's range [sbase, sbase+total) is contiguous; scan emits
//      immutable bstart/bend + mutable gcur. Else unchanged from R11/R12.

#define FEAT 128
#define NHEAD 8
#define NPAD 50048     // N rounded up to multiple of 64
#define ASTRIDE 136    // LDS row stride (bf16 elems): breaks 128-stride conflicts
#define BSH 9          // 512 dests per bucket
#define NBUCK 98       // ceil(50000/512)
#define BCAP 96        // LDS records per bucket (multiple of 16)

typedef __attribute__((ext_vector_type(8))) short bf16x8;
typedef __attribute__((ext_vector_type(4))) float f32x4;

__device__ __forceinline__ unsigned short f2bf(float f) {
    unsigned u = __float_as_uint(f);
    u += 0x7fffu + ((u >> 16) & 1u);
    return (unsigned short)(u >> 16);
}
__device__ __forceinline__ float bf2f_lo(unsigned u) { return __uint_as_float(u << 16); }
__device__ __forceinline__ float bf2f_hi(unsigned u) { return __uint_as_float(u & 0xffff0000u); }
__device__ __forceinline__ float bfw(unsigned short u) { return __uint_as_float((unsigned)u << 16); }

__device__ __forceinline__ bf16x8 cvt8(float4 f0, float4 f1) {
    bf16x8 t;
    t[0] = (short)f2bf(f0.x); t[1] = (short)f2bf(f0.y);
    t[2] = (short)f2bf(f0.z); t[3] = (short)f2bf(f0.w);
    t[4] = (short)f2bf(f1.x); t[5] = (short)f2bf(f1.y);
    t[6] = (short)f2bf(f1.z); t[7] = (short)f2bf(f1.w);
    return t;
}

// ---- hist: dest-degree histogram ----
__global__ __launch_bounds__(256) void hist_kernel(
    const int* __restrict__ dsts, int* __restrict__ counts, int E)
{
    int e = blockIdx.x * 256 + threadIdx.x;
    if (e < E) atomicAdd(counts + dsts[e], 1);
}

// ---- scan: one block per bucket (512 dests, 2 elems/thread).
//      Bucket range [sbase, sbase+total) is contiguous by construction.
//      Emits offsets/cursor per dest, bstart/bend (immutable) and gcur
//      (mutable staging cursor) per bucket. ----
__global__ __launch_bounds__(256) void scan_kernel(
    const int* __restrict__ counts, int* __restrict__ offsets,
    int* __restrict__ cursor, int* __restrict__ gcursor,
    int* __restrict__ bstart, int* __restrict__ bend,
    int* __restrict__ gcur, int N)
{
    __shared__ int buf[256];
    __shared__ int sbase;
    int t = threadIdx.x;
    int base = blockIdx.x << BSH;
    int i0 = base + 2 * t, i1 = i0 + 1;
    int v0 = (i0 < N) ? counts[i0] : 0;
    int v1 = (i1 < N) ? counts[i1] : 0;
    int pv = v0 + v1;
    buf[t] = pv; __syncthreads();
    int x = pv;
    #pragma unroll
    for (int off = 1; off < 256; off <<= 1) {
        int y = (t >= off) ? buf[t - off] : 0;
        __syncthreads();
        x += y; buf[t] = x;
        __syncthreads();
    }
    if (t == 255) sbase = atomicAdd(gcursor, x);   // x == bucket total
    __syncthreads();
    int o0 = sbase + x - pv;
    int o1 = o0 + v0;
    if (i0 < N) { offsets[i0] = o0; cursor[i0] = o0; }
    if (i1 < N) { offsets[i1] = o1; cursor[i1] = o1; }
    if (t == 0) { bstart[blockIdx.x] = sbase; gcur[blockIdx.x] = sbase; }
    if (t == 255) bend[blockIdx.x] = sbase + x;
}

// ---- pass1: bin edges into bucket-contiguous staging (coalesced bursts) ----
// record: s (17b) | dlocal (9b)
__global__ __launch_bounds__(256) void binfill_kernel(
    const int* __restrict__ srcs, const int* __restrict__ dsts,
    int* __restrict__ gcur, unsigned* __restrict__ stg, int E, int EPB)
{
    __shared__ unsigned buf[NBUCK * BCAP];
    __shared__ int cnt[NBUCK];
    const int tid = threadIdx.x;
    const int lane = tid & 63;
    const int wave = tid >> 6;

    for (int i = tid; i < NBUCK; i += 256) cnt[i] = 0;
    __syncthreads();

    const int base = blockIdx.x * EPB;
    const int end = min(base + EPB, E);

    for (int e0 = base; e0 < end; e0 += 256) {
        int e = e0 + tid;
        if (e < end) {
            int s = srcs[e], d = dsts[e];
            int b = d >> BSH;
            unsigned r = (unsigned)s | ((unsigned)(d & 511) << 17);
            int pos = atomicAdd(&cnt[b], 1);
            if (pos < BCAP) buf[b * BCAP + pos] = r;
            else { int gp = atomicAdd(&gcur[b], 1); stg[gp] = r; }  // rare spill
        }
        __syncthreads();
        // flush phase: each wave sweeps its buckets, flushes multiples of 16
        for (int b = wave; b < NBUCK; b += 4) {
            int c = min(cnt[b], BCAP);
            int k = c & ~15;
            if (k > 0) {
                int gbase = 0;
                if (lane == 0) gbase = atomicAdd(&gcur[b], k);
                gbase = __shfl(gbase, 0);
                for (int t2 = lane; t2 < k; t2 += 64)
                    stg[gbase + t2] = buf[b * BCAP + t2];
                int rem = c - k;   // <= 15, disjoint from [0,k) since k >= 16
                unsigned tmp = (lane < rem) ? buf[b * BCAP + k + lane] : 0u;
                if (lane < rem) buf[b * BCAP + lane] = tmp;
                cnt[b] = rem;
            } else {
                cnt[b] = c;
            }
        }
        __syncthreads();
    }
    // final flush: everything, partial bursts allowed
    for (int b = wave; b < NBUCK; b += 4) {
        int c = min(cnt[b], BCAP);
        if (c > 0) {
            int gbase = 0;
            if (lane == 0) gbase = atomicAdd(&gcur[b], c);
            gbase = __shfl(gbase, 0);
            for (int t2 = lane; t2 < c; t2 += 64)
                stg[gbase + t2] = buf[b * BCAP + t2];
        }
    }
}

// ---- pass2: permute each bucket's staged records into dest-CSR order.
//      One block per bucket -> writes stay in one CU's L2 window. ----
__global__ __launch_bounds__(256) void scatter2_kernel(
    const unsigned* __restrict__ stg, const int* __restrict__ bstart,
    const int* __restrict__ bend, int* __restrict__ cursor,
    int* __restrict__ rec, int N)
{
    int b = blockIdx.x;
    int start = bstart[b], end = bend[b];
    int dbase = b << BSH;
    for (int i = start + threadIdx.x; i < end; i += 256) {
        unsigned r = stg[i];
        int s = (int)(r & 0x1FFFFu);
        int d = dbase + (int)(r >> 17);
        int pd = atomicAdd(cursor + d, 1);
        rec[pd] = s;
    }
}

// ---- QKV MFMA GEMM: LDS-staged A (64 rows/iter), B frags from fp32 W ----
__global__ __launch_bounds__(256) void qkv_mfma_kernel(
    const float* __restrict__ X,
    const float* __restrict__ Wq, const float* __restrict__ Wk, const float* __restrict__ Wv,
    const float* __restrict__ bq, const float* __restrict__ bk, const float* __restrict__ bv,
    unsigned short* __restrict__ Q, unsigned short* __restrict__ K,
    unsigned short* __restrict__ V, int N, int numIter)
{
    __shared__ unsigned short As[64 * ASTRIDE];
    const int tid = threadIdx.x;
    const int lane = tid & 63;
    const int wave = tid >> 6;
    const int m = lane & 15, quad = lane >> 4;
    const int colbase = wave * 32;

    const float* Wmat[3] = {Wq, Wk, Wv};
    bf16x8 bfr[3][2][4];
    #pragma unroll
    for (int mat = 0; mat < 3; mat++)
        #pragma unroll
        for (int ctl = 0; ctl < 2; ctl++) {
            const float* wrow = Wmat[mat] + (size_t)(colbase + ctl * 16 + m) * FEAT + quad * 8;
            #pragma unroll
            for (int kc = 0; kc < 4; kc++) {
                float4 f0 = *(const float4*)(wrow + kc * 32);
                float4 f1 = *(const float4*)(wrow + kc * 32 + 4);
                bfr[mat][ctl][kc] = cvt8(f0, f1);
            }
        }

    const float* bias_p[3] = {bq, bk, bv};
    float bias[3][2];
    #pragma unroll
    for (int mat = 0; mat < 3; mat++)
        #pragma unroll
        for (int ctl = 0; ctl < 2; ctl++)
            bias[mat][ctl] = bias_p[mat][colbase + ctl * 16 + m];

    unsigned short* outp[3] = {Q, K, V};

    for (int iter = blockIdx.x; iter < numIter; iter += gridDim.x) {
        const int row0 = iter * 64;
        #pragma unroll
        for (int rep = 0; rep < 8; rep++) {
            int i4 = rep * 256 + tid;
            int r = i4 >> 5;
            int c = (i4 & 31) * 4;
            int gr = row0 + r;
            float4 f = *(const float4*)(X + (size_t)(gr < N ? gr : N - 1) * FEAT + c);
            unsigned lo = (unsigned)f2bf(f.x) | ((unsigned)f2bf(f.y) << 16);
            unsigned hi = (unsigned)f2bf(f.z) | ((unsigned)f2bf(f.w) << 16);
            *(uint2*)(As + r * ASTRIDE + c) = (uint2){lo, hi};
        }
        __syncthreads();

        #pragma unroll
        for (int sub = 0; sub < 4; sub++) {
            const unsigned short* arow = As + (sub * 16 + m) * ASTRIDE + quad * 8;
            bf16x8 a[4];
            #pragma unroll
            for (int kc = 0; kc < 4; kc++) a[kc] = *(const bf16x8*)(arow + kc * 32);
            f32x4 acc[3][2];
            #pragma unroll
            for (int mat = 0; mat < 3; mat++)
                #pragma unroll
                for (int ctl = 0; ctl < 2; ctl++) acc[mat][ctl] = (f32x4){0.f, 0.f, 0.f, 0.f};
            #pragma unroll
            for (int kc = 0; kc < 4; kc++)
                #pragma unroll
                for (int mat = 0; mat < 3; mat++)
                    #pragma unroll
                    for (int ctl = 0; ctl < 2; ctl++)
                        acc[mat][ctl] = __builtin_amdgcn_mfma_f32_16x16x32_bf16(
                            a[kc], bfr[mat][ctl][kc], acc[mat][ctl], 0, 0, 0);
            #pragma unroll
            for (int mat = 0; mat < 3; mat++)
                #pragma unroll
                for (int ctl = 0; ctl < 2; ctl++)
                    #pragma unroll
                    for (int reg = 0; reg < 4; reg++) {
                        int row = row0 + sub * 16 + quad * 4 + reg;
                        if (row < N)
                            outp[mat][(size_t)row * FEAT + colbase + ctl * 16 + m] =
                                f2bf(acc[mat][ctl][reg] + bias[mat][ctl]);
                    }
        }
        __syncthreads();
    }
}

// ---- sumexp: one wave per DEST node, shfl-free (R9) ----
__global__ __launch_bounds__(256) void sumexp_kernel(
    const int* __restrict__ offsets, const int* __restrict__ counts,
    const int* __restrict__ rec,
    const unsigned short* __restrict__ Q, const unsigned short* __restrict__ K,
    unsigned short* __restrict__ wrawb, float* __restrict__ segsum, int N)
{
    int node = blockIdx.x * 4 + (threadIdx.x >> 6);
    if (node >= N) return;
    int lane = threadIdx.x & 63;
    int j = lane >> 3, h = lane & 7;
    int start = offsets[node], deg = counts[node];
    if (deg == 0) return;

    float kf[16];
    {
        const unsigned* kp = (const unsigned*)(K + (size_t)node * FEAT + h * 16);
        #pragma unroll
        for (int i = 0; i < 8; i++) {
            unsigned u = kp[i];
            kf[2 * i]     = bf2f_lo(u);
            kf[2 * i + 1] = bf2f_hi(u);
        }
    }

    for (int j0 = 0; j0 < deg; j0 += 8) {
        int jj = j0 + j;
        bool act = jj < deg;
        int pos = start + (act ? jj : j0);
        int s = rec[pos];
        const unsigned* qp = (const unsigned*)(Q + (size_t)s * FEAT + h * 16);
        uint4 qa = *(const uint4*)qp;
        uint4 qb = *(const uint4*)(qp + 4);
        float p;
        p  = bf2f_lo(qa.x) * kf[0]  + bf2f_hi(qa.x) * kf[1];
        p += bf2f_lo(qa.y) * kf[2]  + bf2f_hi(qa.y) * kf[3];
        p += bf2f_lo(qa.z) * kf[4]  + bf2f_hi(qa.z) * kf[5];
        p += bf2f_lo(qa.w) * kf[6]  + bf2f_hi(qa.w) * kf[7];
        p += bf2f_lo(qb.x) * kf[8]  + bf2f_hi(qb.x) * kf[9];
        p += bf2f_lo(qb.y) * kf[10] + bf2f_hi(qb.y) * kf[11];
        p += bf2f_lo(qb.z) * kf[12] + bf2f_hi(qb.z) * kf[13];
        p += bf2f_lo(qb.w) * kf[14] + bf2f_hi(qb.w) * kf[15];
        float w = __expf(p * 0.25f);
        if (act) {
            wrawb[(size_t)(start + j0) * NHEAD + lane] = f2bf(w);
            atomicAdd(segsum + (size_t)s * NHEAD + h, w);
        }
    }
}

// ---- gather: one wave per dest node; inline v_rcp(segsum[src]) ----
__global__ __launch_bounds__(256) void gather_kernel(
    const int* __restrict__ offsets, const int* __restrict__ counts,
    const int* __restrict__ rec, const unsigned short* __restrict__ wrawb,
    const float* __restrict__ segsum, const unsigned short* __restrict__ V,
    unsigned short* __restrict__ agg, int N)
{
    int node = blockIdx.x * 4 + (threadIdx.x >> 6);
    if (node >= N) return;
    int lane = threadIdx.x & 63;
    int h = lane >> 3;
    int start = offsets[node], deg = counts[node];
    float ax = 0.f, ay = 0.f;
    int j = 0;
    for (; j + 4 <= deg; j += 4) {
        int p = start + j;
        int s0 = rec[p], s1 = rec[p + 1];
        int s2 = rec[p + 2], s3 = rec[p + 3];
        float w0 = bfw(wrawb[(size_t)(p + 0) * NHEAD + h]) *
                   __builtin_amdgcn_rcpf(segsum[(size_t)s0 * NHEAD + h]);
        float w1 = bfw(wrawb[(size_t)(p + 1) * NHEAD + h]) *
                   __builtin_amdgcn_rcpf(segsum[(size_t)s1 * NHEAD + h]);
        float w2 = bfw(wrawb[(size_t)(p + 2) * NHEAD + h]) *
                   __builtin_amdgcn_rcpf(segsum[(size_t)s2 * NHEAD + h]);
        float w3 = bfw(wrawb[(size_t)(p + 3) * NHEAD + h]) *
                   __builtin_amdgcn_rcpf(segsum[(size_t)s3 * NHEAD + h]);
        unsigned v0 = *(const unsigned*)(V + (size_t)s0 * FEAT + lane * 2);
        unsigned v1 = *(const unsigned*)(V + (size_t)s1 * FEAT + lane * 2);
        unsigned v2 = *(const unsigned*)(V + (size_t)s2 * FEAT + lane * 2);
        unsigned v3 = *(const unsigned*)(V + (size_t)s3 * FEAT + lane * 2);
        ax += w0 * bf2f_lo(v0) + w1 * bf2f_lo(v1) + w2 * bf2f_lo(v2) + w3 * bf2f_lo(v3);
        ay += w0 * bf2f_hi(v0) + w1 * bf2f_hi(v1) + w2 * bf2f_hi(v2) + w3 * bf2f_hi(v3);
    }
    for (; j < deg; j++) {
        int p = start + j;
        int s = rec[p];
        float w = bfw(wrawb[(size_t)p * NHEAD + h]) *
                  __builtin_amdgcn_rcpf(segsum[(size_t)s * NHEAD + h]);
        unsigned v = *(const unsigned*)(V + (size_t)s * FEAT + lane * 2);
        ax += w * bf2f_lo(v);
        ay += w * bf2f_hi(v);
    }
    unsigned o = (unsigned)f2bf(ax) | ((unsigned)f2bf(ay) << 16);
    *(unsigned*)(agg + (size_t)node * FEAT + lane * 2) = o;
}

// ---- out MFMA GEMM: B frags from fp32 Wo (in-register cvt), f32 out ----
__global__ __launch_bounds__(256) void out_mfma_kernel(
    const unsigned short* __restrict__ Ab, const float* __restrict__ Wo,
    const float* __restrict__ bo, float* __restrict__ out, int N, int numTiles)
{
    const int lane = threadIdx.x & 63;
    const int wave = threadIdx.x >> 6;
    const int m = lane & 15, quad = lane >> 4;
    const int colbase = wave * 32;

    bf16x8 bfr[2][4];
    #pragma unroll
    for (int ctl = 0; ctl < 2; ctl++) {
        const float* wrow = Wo + (size_t)(colbase + ctl * 16 + m) * FEAT + quad * 8;
        #pragma unroll
        for (int kc = 0; kc < 4; kc++) {
            float4 f0 = *(const float4*)(wrow + kc * 32);
            float4 f1 = *(const float4*)(wrow + kc * 32 + 4);
            bfr[ctl][kc] = cvt8(f0, f1);
        }
    }
    float bias[2];
    #pragma unroll
    for (int ctl = 0; ctl < 2; ctl++) bias[ctl] = bo[colbase + ctl * 16 + m];

    for (int tile = blockIdx.x; tile < numTiles; tile += gridDim.x) {
        const int row0 = tile * 16;
        const unsigned short* arow = Ab + (size_t)(row0 + m) * FEAT + quad * 8;
        bf16x8 a[4];
        #pragma unroll
        for (int kc = 0; kc < 4; kc++) a[kc] = *(const bf16x8*)(arow + kc * 32);
        f32x4 acc[2];
        #pragma unroll
        for (int ctl = 0; ctl < 2; ctl++) acc[ctl] = (f32x4){0.f, 0.f, 0.f, 0.f};
        #pragma unroll
        for (int kc = 0; kc < 4; kc++)
            #pragma unroll
            for (int ctl = 0; ctl < 2; ctl++)
                acc[ctl] = __builtin_amdgcn_mfma_f32_16x16x32_bf16(
                    a[kc], bfr[ctl][kc], acc[ctl], 0, 0, 0);
        #pragma unroll
        for (int ctl = 0; ctl < 2; ctl++)
            #pragma unroll
            for (int reg = 0; reg < 4; reg++) {
                int row = row0 + quad * 4 + reg;
                if (row < N)
                    out[(size_t)row * FEAT + colbase + ctl * 16 + m] = acc[ctl][reg] + bias[ctl];
            }
    }
}

extern "C" void kernel_launch(void* const* d_in, const int* in_sizes, int n_in,
                              void* d_out, int out_size, void* d_ws, size_t ws_size,
                              hipStream_t stream) {
    const float* X  = (const float*)d_in[0];
    const int*   ei = (const int*)d_in[1];
    const float* Wq = (const float*)d_in[2];
    const float* bq = (const float*)d_in[3];
    const float* Wk = (const float*)d_in[4];
    const float* bk = (const float*)d_in[5];
    const float* Wv = (const float*)d_in[6];
    const float* bv = (const float*)d_in[7];
    const float* Wo = (const float*)d_in[8];
    const float* bo = (const float*)d_in[9];
    float* out = (float*)d_out;

    const int N = in_sizes[0] / FEAT;        // 50000
    const int E = in_sizes[1] / 2;           // 600000
    const int* srcs = ei;
    const int* dsts = ei + E;
    const size_t NF2 = (size_t)NPAD * FEAT * 2;

    char* w = (char*)d_ws;
    unsigned short* Qb = (unsigned short*)w;  w += NF2;
    unsigned short* Kb = (unsigned short*)w;  w += NF2;
    unsigned short* Vb = (unsigned short*)w;  w += NF2;
    unsigned short* Ab = (unsigned short*)w;  w += NF2;
    unsigned short* wrawb = (unsigned short*)w; w += (size_t)E * NHEAD * 2;  // bf16
    float* segsum      = (float*)w;           w += (size_t)N * NHEAD * 4;  // zeroed
    int* counts        = (int*)w;             w += (size_t)N * 4;          // zeroed (contig)
    int* gcursor       = (int*)w;             w += 4;                      // zeroed (contig)
    int* offsets       = (int*)w;             w += (size_t)N * 4;
    int* cursor        = (int*)w;             w += (size_t)N * 4;
    int* bstart        = (int*)w;             w += 128 * 4;
    int* bend          = (int*)w;             w += 128 * 4;
    int* gcur          = (int*)w;             w += 128 * 4;
    int* rec           = (int*)w;             w += (size_t)E * 4;
    unsigned* stg      = (unsigned*)w;        w += (size_t)E * 4;

    // zero segsum + counts + gcursor (contiguous)
    hipMemsetAsync(segsum, 0, (size_t)N * NHEAD * 4 + (size_t)N * 4 + 4, stream);

    int e_blocks = (E + 255) / 256;          // 2344
    hist_kernel<<<e_blocks, 256, 0, stream>>>(dsts, counts, E);

    scan_kernel<<<NBUCK, 256, 0, stream>>>(
        counts, offsets, cursor, gcursor, bstart, bend, gcur, N);

    int p1_blocks = 392;
    int EPB = (E + p1_blocks - 1) / p1_blocks;   // 1531
    binfill_kernel<<<p1_blocks, 256, 0, stream>>>(srcs, dsts, gcur, stg, E, EPB);

    scatter2_kernel<<<NBUCK, 256, 0, stream>>>(stg, bstart, bend, cursor, rec, N);

    int numIter = NPAD / 64;    // 782
    qkv_mfma_kernel<<<391, 256, 0, stream>>>(
        X, Wq, Wk, Wv, bq, bk, bv, Qb, Kb, Vb, N, numIter);

    int node_blocks = (N + 3) / 4;
    sumexp_kernel<<<node_blocks, 256, 0, stream>>>(
        offsets, counts, rec, Qb, Kb, wrawb, segsum, N);

    gather_kernel<<<node_blocks, 256, 0, stream>>>(
        offsets, counts, rec, wrawb, segsum, Vb, Ab, N);

    int numTiles = NPAD / 16;   // 3128
    out_mfma_kernel<<<782, 256, 0, stream>>>(Ab, Wo, bo, out, N, numTiles);
}

// Round 14
// 282.829 us; speedup vs baseline: 1.6294x; 1.6294x over previous
//
#include <hip/hip_runtime.h>
#include <hip/hip_bf16.h>

// GAT-style graph attention. N=50000, E=600000, FEAT=128, H=8, D=16.
// R14: revert binned fill (R12 crashed; R13 binfill was 4x slower than the
//      naive scatter - LDS atomic serialization, 177k bank-conflict cycles).
//      Naive one-pass fill (~47us, XCD line-writeback bound) is accepted.
//      Keeps: single-kernel bucket scan, R11 LDS-staged qkv at grid=782
//      (1 iter/block, was 2 -> raise occupancy/MLP), shfl-free sumexp,
//      bf16 wraw, inline rcp gather, persistent-B MFMA out.

#define FEAT 128
#define NHEAD 8
#define NPAD 50048     // N rounded up to multiple of 64
#define ASTRIDE 136    // LDS row stride (bf16 elems): breaks 128-stride conflicts
#define BSH 9          // 512 dests per scan block
#define NBUCK 98       // ceil(50000/512)

typedef __attribute__((ext_vector_type(8))) short bf16x8;
typedef __attribute__((ext_vector_type(4))) float f32x4;

__device__ __forceinline__ unsigned short f2bf(float f) {
    unsigned u = __float_as_uint(f);
    u += 0x7fffu + ((u >> 16) & 1u);
    return (unsigned short)(u >> 16);
}
__device__ __forceinline__ float bf2f_lo(unsigned u) { return __uint_as_float(u << 16); }
__device__ __forceinline__ float bf2f_hi(unsigned u) { return __uint_as_float(u & 0xffff0000u); }
__device__ __forceinline__ float bfw(unsigned short u) { return __uint_as_float((unsigned)u << 16); }

__device__ __forceinline__ bf16x8 cvt8(float4 f0, float4 f1) {
    bf16x8 t;
    t[0] = (short)f2bf(f0.x); t[1] = (short)f2bf(f0.y);
    t[2] = (short)f2bf(f0.z); t[3] = (short)f2bf(f0.w);
    t[4] = (short)f2bf(f1.x); t[5] = (short)f2bf(f1.y);
    t[6] = (short)f2bf(f1.z); t[7] = (short)f2bf(f1.w);
    return t;
}

// ---- hist: dest-degree histogram ----
__global__ __launch_bounds__(256) void hist_kernel(
    const int* __restrict__ dsts, int* __restrict__ counts, int E)
{
    int e = blockIdx.x * 256 + threadIdx.x;
    if (e < E) atomicAdd(counts + dsts[e], 1);
}

// ---- scan: one block per 512-dest bucket, block base via global atomic.
//      Any disjoint partition of [0,E) is a valid CSR. ----
__global__ __launch_bounds__(256) void scan_kernel(
    const int* __restrict__ counts, int* __restrict__ offsets,
    int* __restrict__ cursor, int* __restrict__ gcursor, int N)
{
    __shared__ int buf[256];
    __shared__ int sbase;
    int t = threadIdx.x;
    int base = blockIdx.x << BSH;
    int i0 = base + 2 * t, i1 = i0 + 1;
    int v0 = (i0 < N) ? counts[i0] : 0;
    int v1 = (i1 < N) ? counts[i1] : 0;
    int pv = v0 + v1;
    buf[t] = pv; __syncthreads();
    int x = pv;
    #pragma unroll
    for (int off = 1; off < 256; off <<= 1) {
        int y = (t >= off) ? buf[t - off] : 0;
        __syncthreads();
        x += y; buf[t] = x;
        __syncthreads();
    }
    if (t == 255) sbase = atomicAdd(gcursor, x);   // x == bucket total
    __syncthreads();
    int o0 = sbase + x - pv;
    int o1 = o0 + v0;
    if (i0 < N) { offsets[i0] = o0; cursor[i0] = o0; }
    if (i1 < N) { offsets[i1] = o1; cursor[i1] = o1; }
}

// ---- fill dest-CSR: ONE scattered 4B stream (accepted ~47us cost) ----
__global__ __launch_bounds__(256) void fill_kernel(
    const int* __restrict__ srcs, const int* __restrict__ dsts,
    int* __restrict__ cursor, int* __restrict__ rec, int E)
{
    int e = blockIdx.x * 256 + threadIdx.x;
    if (e < E) {
        int s = srcs[e], d = dsts[e];
        int pd = atomicAdd(cursor + d, 1);
        __builtin_nontemporal_store(s, rec + pd);
    }
}

// ---- QKV MFMA GEMM: LDS-staged A (64 rows/block), B frags from fp32 W ----
__global__ __launch_bounds__(256) void qkv_mfma_kernel(
    const float* __restrict__ X,
    const float* __restrict__ Wq, const float* __restrict__ Wk, const float* __restrict__ Wv,
    const float* __restrict__ bq, const float* __restrict__ bk, const float* __restrict__ bv,
    unsigned short* __restrict__ Q, unsigned short* __restrict__ K,
    unsigned short* __restrict__ V, int N, int numIter)
{
    __shared__ unsigned short As[64 * ASTRIDE];
    const int tid = threadIdx.x;
    const int lane = tid & 63;
    const int wave = tid >> 6;
    const int m = lane & 15, quad = lane >> 4;
    const int colbase = wave * 32;

    const float* Wmat[3] = {Wq, Wk, Wv};
    bf16x8 bfr[3][2][4];
    #pragma unroll
    for (int mat = 0; mat < 3; mat++)
        #pragma unroll
        for (int ctl = 0; ctl < 2; ctl++) {
            const float* wrow = Wmat[mat] + (size_t)(colbase + ctl * 16 + m) * FEAT + quad * 8;
            #pragma unroll
            for (int kc = 0; kc < 4; kc++) {
                float4 f0 = *(const float4*)(wrow + kc * 32);
                float4 f1 = *(const float4*)(wrow + kc * 32 + 4);
                bfr[mat][ctl][kc] = cvt8(f0, f1);
            }
        }

    const float* bias_p[3] = {bq, bk, bv};
    float bias[3][2];
    #pragma unroll
    for (int mat = 0; mat < 3; mat++)
        #pragma unroll
        for (int ctl = 0; ctl < 2; ctl++)
            bias[mat][ctl] = bias_p[mat][colbase + ctl * 16 + m];

    unsigned short* outp[3] = {Q, K, V};

    for (int iter = blockIdx.x; iter < numIter; iter += gridDim.x) {
        const int row0 = iter * 64;
        #pragma unroll
        for (int rep = 0; rep < 8; rep++) {
            int i4 = rep * 256 + tid;
            int r = i4 >> 5;
            int c = (i4 & 31) * 4;
            int gr = row0 + r;
            float4 f = *(const float4*)(X + (size_t)(gr < N ? gr : N - 1) * FEAT + c);
            unsigned lo = (unsigned)f2bf(f.x) | ((unsigned)f2bf(f.y) << 16);
            unsigned hi = (unsigned)f2bf(f.z) | ((unsigned)f2bf(f.w) << 16);
            *(uint2*)(As + r * ASTRIDE + c) = (uint2){lo, hi};
        }
        __syncthreads();

        #pragma unroll
        for (int sub = 0; sub < 4; sub++) {
            const unsigned short* arow = As + (sub * 16 + m) * ASTRIDE + quad * 8;
            bf16x8 a[4];
            #pragma unroll
            for (int kc = 0; kc < 4; kc++) a[kc] = *(const bf16x8*)(arow + kc * 32);
            f32x4 acc[3][2];
            #pragma unroll
            for (int mat = 0; mat < 3; mat++)
                #pragma unroll
                for (int ctl = 0; ctl < 2; ctl++) acc[mat][ctl] = (f32x4){0.f, 0.f, 0.f, 0.f};
            #pragma unroll
            for (int kc = 0; kc < 4; kc++)
                #pragma unroll
                for (int mat = 0; mat < 3; mat++)
                    #pragma unroll
                    for (int ctl = 0; ctl < 2; ctl++)
                        acc[mat][ctl] = __builtin_amdgcn_mfma_f32_16x16x32_bf16(
                            a[kc], bfr[mat][ctl][kc], acc[mat][ctl], 0, 0, 0);
            #pragma unroll
            for (int mat = 0; mat < 3; mat++)
                #pragma unroll
                for (int ctl = 0; ctl < 2; ctl++)
                    #pragma unroll
                    for (int reg = 0; reg < 4; reg++) {
                        int row = row0 + sub * 16 + quad * 4 + reg;
                        if (row < N)
                            outp[mat][(size_t)row * FEAT + colbase + ctl * 16 + m] =
                                f2bf(acc[mat][ctl][reg] + bias[mat][ctl]);
                    }
        }
        __syncthreads();
    }
}

// ---- sumexp: one wave per DEST node, shfl-free (R9) ----
__global__ __launch_bounds__(256) void sumexp_kernel(
    const int* __restrict__ offsets, const int* __restrict__ counts,
    const int* __restrict__ rec,
    const unsigned short* __restrict__ Q, const unsigned short* __restrict__ K,
    unsigned short* __restrict__ wrawb, float* __restrict__ segsum, int N)
{
    int node = blockIdx.x * 4 + (threadIdx.x >> 6);
    if (node >= N) return;
    int lane = threadIdx.x & 63;
    int j = lane >> 3, h = lane & 7;
    int start = offsets[node], deg = counts[node];
    if (deg == 0) return;

    float kf[16];
    {
        const unsigned* kp = (const unsigned*)(K + (size_t)node * FEAT + h * 16);
        #pragma unroll
        for (int i = 0; i < 8; i++) {
            unsigned u = kp[i];
            kf[2 * i]     = bf2f_lo(u);
            kf[2 * i + 1] = bf2f_hi(u);
        }
    }

    for (int j0 = 0; j0 < deg; j0 += 8) {
        int jj = j0 + j;
        bool act = jj < deg;
        int pos = start + (act ? jj : j0);
        int s = rec[pos];
        const unsigned* qp = (const unsigned*)(Q + (size_t)s * FEAT + h * 16);
        uint4 qa = *(const uint4*)qp;
        uint4 qb = *(const uint4*)(qp + 4);
        float p;
        p  = bf2f_lo(qa.x) * kf[0]  + bf2f_hi(qa.x) * kf[1];
        p += bf2f_lo(qa.y) * kf[2]  + bf2f_hi(qa.y) * kf[3];
        p += bf2f_lo(qa.z) * kf[4]  + bf2f_hi(qa.z) * kf[5];
        p += bf2f_lo(qa.w) * kf[6]  + bf2f_hi(qa.w) * kf[7];
        p += bf2f_lo(qb.x) * kf[8]  + bf2f_hi(qb.x) * kf[9];
        p += bf2f_lo(qb.y) * kf[10] + bf2f_hi(qb.y) * kf[11];
        p += bf2f_lo(qb.z) * kf[12] + bf2f_hi(qb.z) * kf[13];
        p += bf2f_lo(qb.w) * kf[14] + bf2f_hi(qb.w) * kf[15];
        float w = __expf(p * 0.25f);
        if (act) {
            wrawb[(size_t)(start + j0) * NHEAD + lane] = f2bf(w);
            atomicAdd(segsum + (size_t)s * NHEAD + h, w);
        }
    }
}

// ---- gather: one wave per dest node; inline v_rcp(segsum[src]) ----
__global__ __launch_bounds__(256) void gather_kernel(
    const int* __restrict__ offsets, const int* __restrict__ counts,
    const int* __restrict__ rec, const unsigned short* __restrict__ wrawb,
    const float* __restrict__ segsum, const unsigned short* __restrict__ V,
    unsigned short* __restrict__ agg, int N)
{
    int node = blockIdx.x * 4 + (threadIdx.x >> 6);
    if (node >= N) return;
    int lane = threadIdx.x & 63;
    int h = lane >> 3;
    int start = offsets[node], deg = counts[node];
    float ax = 0.f, ay = 0.f;
    int j = 0;
    for (; j + 4 <= deg; j += 4) {
        int p = start + j;
        int s0 = rec[p], s1 = rec[p + 1];
        int s2 = rec[p + 2], s3 = rec[p + 3];
        float w0 = bfw(wrawb[(size_t)(p + 0) * NHEAD + h]) *
                   __builtin_amdgcn_rcpf(segsum[(size_t)s0 * NHEAD + h]);
        float w1 = bfw(wrawb[(size_t)(p + 1) * NHEAD + h]) *
                   __builtin_amdgcn_rcpf(segsum[(size_t)s1 * NHEAD + h]);
        float w2 = bfw(wrawb[(size_t)(p + 2) * NHEAD + h]) *
                   __builtin_amdgcn_rcpf(segsum[(size_t)s2 * NHEAD + h]);
        float w3 = bfw(wrawb[(size_t)(p + 3) * NHEAD + h]) *
                   __builtin_amdgcn_rcpf(segsum[(size_t)s3 * NHEAD + h]);
        unsigned v0 = *(const unsigned*)(V + (size_t)s0 * FEAT + lane * 2);
        unsigned v1 = *(const unsigned*)(V + (size_t)s1 * FEAT + lane * 2);
        unsigned v2 = *(const unsigned*)(V + (size_t)s2 * FEAT + lane * 2);
        unsigned v3 = *(const unsigned*)(V + (size_t)s3 * FEAT + lane * 2);
        ax += w0 * bf2f_lo(v0) + w1 * bf2f_lo(v1) + w2 * bf2f_lo(v2) + w3 * bf2f_lo(v3);
        ay += w0 * bf2f_hi(v0) + w1 * bf2f_hi(v1) + w2 * bf2f_hi(v2) + w3 * bf2f_hi(v3);
    }
    for (; j < deg; j++) {
        int p = start + j;
        int s = rec[p];
        float w = bfw(wrawb[(size_t)p * NHEAD + h]) *
                  __builtin_amdgcn_rcpf(segsum[(size_t)s * NHEAD + h]);
        unsigned v = *(const unsigned*)(V + (size_t)s * FEAT + lane * 2);
        ax += w * bf2f_lo(v);
        ay += w * bf2f_hi(v);
    }
    unsigned o = (unsigned)f2bf(ax) | ((unsigned)f2bf(ay) << 16);
    *(unsigned*)(agg + (size_t)node * FEAT + lane * 2) = o;
}

// ---- out MFMA GEMM: B frags from fp32 Wo (in-register cvt), f32 out ----
__global__ __launch_bounds__(256) void out_mfma_kernel(
    const unsigned short* __restrict__ Ab, const float* __restrict__ Wo,
    const float* __restrict__ bo, float* __restrict__ out, int N, int numTiles)
{
    const int lane = threadIdx.x & 63;
    const int wave = threadIdx.x >> 6;
    const int m = lane & 15, quad = lane >> 4;
    const int colbase = wave * 32;

    bf16x8 bfr[2][4];
    #pragma unroll
    for (int ctl = 0; ctl < 2; ctl++) {
        const float* wrow = Wo + (size_t)(colbase + ctl * 16 + m) * FEAT + quad * 8;
        #pragma unroll
        for (int kc = 0; kc < 4; kc++) {
            float4 f0 = *(const float4*)(wrow + kc * 32);
            float4 f1 = *(const float4*)(wrow + kc * 32 + 4);
            bfr[ctl][kc] = cvt8(f0, f1);
        }
    }
    float bias[2];
    #pragma unroll
    for (int ctl = 0; ctl < 2; ctl++) bias[ctl] = bo[colbase + ctl * 16 + m];

    for (int tile = blockIdx.x; tile < numTiles; tile += gridDim.x) {
        const int row0 = tile * 16;
        const unsigned short* arow = Ab + (size_t)(row0 + m) * FEAT + quad * 8;
        bf16x8 a[4];
        #pragma unroll
        for (int kc = 0; kc < 4; kc++) a[kc] = *(const bf16x8*)(arow + kc * 32);
        f32x4 acc[2];
        #pragma unroll
        for (int ctl = 0; ctl < 2; ctl++) acc[ctl] = (f32x4){0.f, 0.f, 0.f, 0.f};
        #pragma unroll
        for (int kc = 0; kc < 4; kc++)
            #pragma unroll
            for (int ctl = 0; ctl < 2; ctl++)
                acc[ctl] = __builtin_amdgcn_mfma_f32_16x16x32_bf16(
                    a[kc], bfr[ctl][kc], acc[ctl], 0, 0, 0);
        #pragma unroll
        for (int ctl = 0; ctl < 2; ctl++)
            #pragma unroll
            for (int reg = 0; reg < 4; reg++) {
                int row = row0 + quad * 4 + reg;
                if (row < N)
                    out[(size_t)row * FEAT + colbase + ctl * 16 + m] = acc[ctl][reg] + bias[ctl];
            }
    }
}

extern "C" void kernel_launch(void* const* d_in, const int* in_sizes, int n_in,
                              void* d_out, int out_size, void* d_ws, size_t ws_size,
                              hipStream_t stream) {
    const float* X  = (const float*)d_in[0];
    const int*   ei = (const int*)d_in[1];
    const float* Wq = (const float*)d_in[2];
    const float* bq = (const float*)d_in[3];
    const float* Wk = (const float*)d_in[4];
    const float* bk = (const float*)d_in[5];
    const float* Wv = (const float*)d_in[6];
    const float* bv = (const float*)d_in[7];
    const float* Wo = (const float*)d_in[8];
    const float* bo = (const float*)d_in[9];
    float* out = (float*)d_out;

    const int N = in_sizes[0] / FEAT;        // 50000
    const int E = in_sizes[1] / 2;           // 600000
    const int* srcs = ei;
    const int* dsts = ei + E;
    const size_t NF2 = (size_t)NPAD * FEAT * 2;

    char* w = (char*)d_ws;
    unsigned short* Qb = (unsigned short*)w;  w += NF2;
    unsigned short* Kb = (unsigned short*)w;  w += NF2;
    unsigned short* Vb = (unsigned short*)w;  w += NF2;
    unsigned short* Ab = (unsigned short*)w;  w += NF2;
    unsigned short* wrawb = (unsigned short*)w; w += (size_t)E * NHEAD * 2;  // bf16
    float* segsum      = (float*)w;           w += (size_t)N * NHEAD * 4;  // zeroed
    int* counts        = (int*)w;             w += (size_t)N * 4;          // zeroed (contig)
    int* gcursor       = (int*)w;             w += 4;                      // zeroed (contig)
    int* offsets       = (int*)w;             w += (size_t)N * 4;
    int* cursor        = (int*)w;             w += (size_t)N * 4;
    int* rec           = (int*)w;             w += (size_t)E * 4;

    // zero segsum + counts + gcursor (contiguous)
    hipMemsetAsync(segsum, 0, (size_t)N * NHEAD * 4 + (size_t)N * 4 + 4, stream);

    int e_blocks = (E + 255) / 256;          // 2344
    hist_kernel<<<e_blocks, 256, 0, stream>>>(dsts, counts, E);

    scan_kernel<<<NBUCK, 256, 0, stream>>>(counts, offsets, cursor, gcursor, N);

    fill_kernel<<<e_blocks, 256, 0, stream>>>(srcs, dsts, cursor, rec, E);

    int numIter = NPAD / 64;    // 782
    qkv_mfma_kernel<<<782, 256, 0, stream>>>(
        X, Wq, Wk, Wv, bq, bk, bv, Qb, Kb, Vb, N, numIter);

    int node_blocks = (N + 3) / 4;
    sumexp_kernel<<<node_blocks, 256, 0, stream>>>(
        offsets, counts, rec, Qb, Kb, wrawb, segsum, N);

    gather_kernel<<<node_blocks, 256, 0, stream>>>(
        offsets, counts, rec, wrawb, segsum, Vb, Ab, N);

    int numTiles = NPAD / 16;   // 3128
    out_mfma_kernel<<<782, 256, 0, stream>>>(Ab, Wo, bo, out, N, numTiles);
}